// Round 2
// baseline (6931.732 us; speedup 1.0000x reference)
//
#include <hip/hip_runtime.h>
#include <hip/hip_bf16.h>
#include <hip/hip_cooperative_groups.h>

namespace cg = cooperative_groups;

constexpr int B = 512;
constexpr int I = 512;
constexpr int H = 1024;
constexpr int O = 512;

using short8 = __attribute__((ext_vector_type(8))) short;
using f32x4  = __attribute__((ext_vector_type(4))) float;
using bf16_t = __hip_bfloat16;

__device__ __forceinline__ short8 ldfrag(const bf16_t* p) {
    return *reinterpret_cast<const short8*>(p);
}

__device__ __forceinline__ float sigmoid_f(float z) {
    return 1.0f / (1.0f + __expf(-z));
}

// Persistent cooperative kernel: weight cast, jx/kx precompute, full T-step
// recurrence with one grid sync per step (double-buffered bf16 h).
// d_out is fp32 (reference output dtype): [B,T,O] outputs then [B,H] h_final.
__global__ __launch_bounds__(256, 1)
void flipflop_rnn_kernel(const float* __restrict__ x,  const float* __restrict__ h0,
                         const float* __restrict__ Wjx, const float* __restrict__ bjx,
                         const float* __restrict__ Wjh, const float* __restrict__ bjh,
                         const float* __restrict__ Wkx, const float* __restrict__ bkx,
                         const float* __restrict__ Wkh, const float* __restrict__ bkh,
                         const float* __restrict__ Wo,  const float* __restrict__ bo,
                         const int* __restrict__ seqlen,
                         float* __restrict__ out,
                         bf16_t* __restrict__ wjh_bf, bf16_t* __restrict__ wkh_bf,
                         bf16_t* __restrict__ wo_bf,  bf16_t* __restrict__ wjx_bf,
                         bf16_t* __restrict__ wkx_bf, bf16_t* __restrict__ x_bf,
                         bf16_t* __restrict__ hbf0,   bf16_t* __restrict__ hbf1)
{
    const int T    = seqlen[0];
    const int tid  = threadIdx.x;
    const int wg   = blockIdx.x;
    const int nthr = gridDim.x * blockDim.x;
    const int gtid = wg * blockDim.x + tid;

    // ---- phase -2: cast weights & x to bf16 (grid-stride) ----
    for (int idx = gtid; idx < H * H; idx += nthr) wjh_bf[idx] = __float2bfloat16(Wjh[idx]);
    for (int idx = gtid; idx < H * H; idx += nthr) wkh_bf[idx] = __float2bfloat16(Wkh[idx]);
    for (int idx = gtid; idx < O * H; idx += nthr) wo_bf[idx]  = __float2bfloat16(Wo[idx]);
    for (int idx = gtid; idx < H * I; idx += nthr) wjx_bf[idx] = __float2bfloat16(Wjx[idx]);
    for (int idx = gtid; idx < H * I; idx += nthr) wkx_bf[idx] = __float2bfloat16(Wkx[idx]);
    for (int idx = gtid; idx < B * I; idx += nthr) x_bf[idx]   = __float2bfloat16(x[idx]);

    // ---- tile/lane geometry ----
    const int w     = tid >> 6;        // wave 0..3
    const int lane  = tid & 63;
    const int quad  = lane >> 4;       // 0..3
    const int lm    = lane & 15;
    const int iblk  = wg >> 5;         // 0..7  : batch-row block (64 rows)
    const int lblk  = wg & 31;         // 0..31 : gate-col block (32) / out-col block (16)
    const int rbase = iblk * 64 + w * 16;  // this wave's 16 batch rows
    const int n0    = lblk * 32;           // gate columns
    const int no0   = lblk * 16;           // out columns

    // ---- init owned h elements (registers) + hbf0 ----
    float hreg[8];
    #pragma unroll
    for (int nt = 0; nt < 2; ++nt)
        #pragma unroll
        for (int r = 0; r < 4; ++r) {
            const int row = rbase + quad * 4 + r;
            const int col = n0 + nt * 16 + lm;
            const float hv = h0[row * H + col];
            hreg[nt * 4 + r] = hv;
            hbf0[row * H + col] = __float2bfloat16(hv);
        }

    cg::this_grid().sync();

    // ---- phase -1: jx/kx = x@W*x^T + biases, kept entirely in registers ----
    float jxr[8], kxr[8];
    {
        f32x4 aJ[2] = {{0.f,0.f,0.f,0.f},{0.f,0.f,0.f,0.f}};
        f32x4 aK[2] = {{0.f,0.f,0.f,0.f},{0.f,0.f,0.f,0.f}};
        const bf16_t* aP  = x_bf   + (rbase + lm) * I + quad * 8;
        const bf16_t* j0P = wjx_bf + (n0 + lm) * I + quad * 8;
        const bf16_t* j1P = wjx_bf + (n0 + 16 + lm) * I + quad * 8;
        const bf16_t* k0P = wkx_bf + (n0 + lm) * I + quad * 8;
        const bf16_t* k1P = wkx_bf + (n0 + 16 + lm) * I + quad * 8;
        #pragma unroll 4
        for (int k0 = 0; k0 < I; k0 += 32) {
            short8 a = ldfrag(aP + k0);
            aJ[0] = __builtin_amdgcn_mfma_f32_16x16x32_bf16(a, ldfrag(j0P + k0), aJ[0], 0, 0, 0);
            aJ[1] = __builtin_amdgcn_mfma_f32_16x16x32_bf16(a, ldfrag(j1P + k0), aJ[1], 0, 0, 0);
            aK[0] = __builtin_amdgcn_mfma_f32_16x16x32_bf16(a, ldfrag(k0P + k0), aK[0], 0, 0, 0);
            aK[1] = __builtin_amdgcn_mfma_f32_16x16x32_bf16(a, ldfrag(k1P + k0), aK[1], 0, 0, 0);
        }
        #pragma unroll
        for (int nt = 0; nt < 2; ++nt)
            #pragma unroll
            for (int r = 0; r < 4; ++r) {
                const int col = n0 + nt * 16 + lm;
                jxr[nt * 4 + r] = aJ[nt][r] + bjx[col] + bjh[col];
                kxr[nt * 4 + r] = aK[nt][r] + bkx[col] + bkh[col];
            }
    }

    const float bo_v = bo[no0 + lm];
    bf16_t* hbufs[2] = {hbf0, hbf1};
    int p = 0;

    // ---- main recurrence: iteration t computes h_{t+1} and out_{t-1} ----
    for (int t = 0; t < T; ++t) {
        cg::this_grid().sync();   // h_bf[p] = h_t complete & visible device-wide
        const bf16_t* hb  = hbufs[p];
        bf16_t*       hbn = hbufs[p ^ 1];

        f32x4 accJ[2] = {{0.f,0.f,0.f,0.f},{0.f,0.f,0.f,0.f}};
        f32x4 accK[2] = {{0.f,0.f,0.f,0.f},{0.f,0.f,0.f,0.f}};
        f32x4 accO    = {0.f,0.f,0.f,0.f};

        const bf16_t* aP  = hb     + (rbase + lm) * H + quad * 8;
        const bf16_t* j0P = wjh_bf + (n0 + lm) * H + quad * 8;
        const bf16_t* j1P = wjh_bf + (n0 + 16 + lm) * H + quad * 8;
        const bf16_t* k0P = wkh_bf + (n0 + lm) * H + quad * 8;
        const bf16_t* k1P = wkh_bf + (n0 + 16 + lm) * H + quad * 8;
        const bf16_t* oP  = wo_bf  + (no0 + lm) * H + quad * 8;

        #pragma unroll 4
        for (int k0 = 0; k0 < H; k0 += 32) {
            short8 a = ldfrag(aP + k0);   // shared A-frag: gates + out GEMMs
            accJ[0] = __builtin_amdgcn_mfma_f32_16x16x32_bf16(a, ldfrag(j0P + k0), accJ[0], 0, 0, 0);
            accJ[1] = __builtin_amdgcn_mfma_f32_16x16x32_bf16(a, ldfrag(j1P + k0), accJ[1], 0, 0, 0);
            accK[0] = __builtin_amdgcn_mfma_f32_16x16x32_bf16(a, ldfrag(k0P + k0), accK[0], 0, 0, 0);
            accK[1] = __builtin_amdgcn_mfma_f32_16x16x32_bf16(a, ldfrag(k1P + k0), accK[1], 0, 0, 0);
            accO    = __builtin_amdgcn_mfma_f32_16x16x32_bf16(a, ldfrag(oP  + k0), accO,    0, 0, 0);
        }

        if (t > 0) {  // out_{t-1} = h_t @ Wo^T + bo  (fp32 store)
            #pragma unroll
            for (int r = 0; r < 4; ++r) {
                const int row = rbase + quad * 4 + r;
                out[(row * T + (t - 1)) * O + no0 + lm] = accO[r] + bo_v;
            }
        }

        // h update (owner-thread registers; write bf16 for next step)
        #pragma unroll
        for (int nt = 0; nt < 2; ++nt)
            #pragma unroll
            for (int r = 0; r < 4; ++r) {
                const int row = rbase + quad * 4 + r;
                const int col = n0 + nt * 16 + lm;
                const float zj = accJ[nt][r] + jxr[nt * 4 + r];
                const float zk = accK[nt][r] + kxr[nt * 4 + r];
                const float jv = sigmoid_f(zj);
                const float kv = sigmoid_f(zk);
                const float hv = hreg[nt * 4 + r];
                const float hn = jv * (1.0f - hv) + (1.0f - kv) * hv;
                hreg[nt * 4 + r] = hn;
                hbn[row * H + col] = __float2bfloat16(hn);
            }
        p ^= 1;
    }

    cg::this_grid().sync();   // h_bf[p] = h_T complete

    // ---- epilogue: out_{T-1} and h_final (fp32) ----
    {
        const bf16_t* hb = hbufs[p];
        f32x4 accO = {0.f, 0.f, 0.f, 0.f};
        const bf16_t* aP = hb    + (rbase + lm) * H + quad * 8;
        const bf16_t* oP = wo_bf + (no0 + lm) * H + quad * 8;
        #pragma unroll 4
        for (int k0 = 0; k0 < H; k0 += 32) {
            accO = __builtin_amdgcn_mfma_f32_16x16x32_bf16(ldfrag(aP + k0), ldfrag(oP + k0), accO, 0, 0, 0);
        }
        #pragma unroll
        for (int r = 0; r < 4; ++r) {
            const int row = rbase + quad * 4 + r;
            out[(row * T + (T - 1)) * O + no0 + lm] = accO[r] + bo_v;
        }
        const int hfin = B * T * O;
        #pragma unroll
        for (int nt = 0; nt < 2; ++nt)
            #pragma unroll
            for (int r = 0; r < 4; ++r) {
                const int row = rbase + quad * 4 + r;
                const int col = n0 + nt * 16 + lm;
                out[hfin + row * H + col] = hreg[nt * 4 + r];
            }
    }
}

extern "C" void kernel_launch(void* const* d_in, const int* in_sizes, int n_in,
                              void* d_out, int out_size, void* d_ws, size_t ws_size,
                              hipStream_t stream) {
    const float* x   = (const float*)d_in[0];
    const float* h0  = (const float*)d_in[1];
    const float* Wjx = (const float*)d_in[2];
    const float* bjx = (const float*)d_in[3];
    const float* Wjh = (const float*)d_in[4];
    const float* bjh = (const float*)d_in[5];
    const float* Wkx = (const float*)d_in[6];
    const float* bkx = (const float*)d_in[7];
    const float* Wkh = (const float*)d_in[8];
    const float* bkh = (const float*)d_in[9];
    const float* Wo  = (const float*)d_in[10];
    const float* bo  = (const float*)d_in[11];
    const int* seqlen = (const int*)d_in[12];
    float* out = (float*)d_out;

    // workspace layout (bytes)
    char* ws = (char*)d_ws;
    bf16_t* wjh_bf = (bf16_t*)(ws + 0);                 // 2 MB
    bf16_t* wkh_bf = (bf16_t*)(ws + 2097152);           // 2 MB
    bf16_t* wo_bf  = (bf16_t*)(ws + 4194304);           // 1 MB
    bf16_t* wjx_bf = (bf16_t*)(ws + 5242880);           // 1 MB
    bf16_t* wkx_bf = (bf16_t*)(ws + 6291456);           // 1 MB
    bf16_t* x_bf   = (bf16_t*)(ws + 7340032);           // 0.5 MB
    bf16_t* hbf0   = (bf16_t*)(ws + 7864320);           // 1 MB
    bf16_t* hbf1   = (bf16_t*)(ws + 8912896);           // 1 MB  (total 9.5 MB)

    void* args[] = {
        &x, &h0, &Wjx, &bjx, &Wjh, &bjh, &Wkx, &bkx, &Wkh, &bkh, &Wo, &bo,
        &seqlen, &out,
        &wjh_bf, &wkh_bf, &wo_bf, &wjx_bf, &wkx_bf, &x_bf, &hbf0, &hbf1
    };
    hipLaunchCooperativeKernel((const void*)flipflop_rnn_kernel,
                               dim3(256), dim3(256), args, 0, stream);
}

// Round 3
// 5503.036 us; speedup vs baseline: 1.2596x; 1.2596x over previous
//
#include <hip/hip_runtime.h>
#include <hip/hip_bf16.h>
#include <hip/hip_cooperative_groups.h>

namespace cg = cooperative_groups;

constexpr int B = 512;
constexpr int I = 512;
constexpr int H = 1024;
constexpr int O = 512;

using short8 = __attribute__((ext_vector_type(8))) short;
using f32x4  = __attribute__((ext_vector_type(4))) float;
using bf16_t = __hip_bfloat16;

__device__ __forceinline__ short8 ldfrag(const bf16_t* p) {
    return *reinterpret_cast<const short8*>(p);
}
__device__ __forceinline__ float sigmoid_f(float z) {
    return 1.0f / (1.0f + __expf(-z));
}

// Per-iblk group barrier: 64 WGs per group, XCD-local (iblk = blockIdx % 8).
__device__ __forceinline__ void group_wait(int* c, int target) {
    if (threadIdx.x == 0) {
        while (__hip_atomic_load(c, __ATOMIC_RELAXED, __HIP_MEMORY_SCOPE_AGENT) < target)
            __builtin_amdgcn_s_sleep(2);
    }
    __syncthreads();
    __builtin_amdgcn_fence(__ATOMIC_ACQUIRE, "agent");  // per-thread acquire (cache inv)
}
__device__ __forceinline__ void group_post(int* c) {
    __syncthreads();  // all WG h-stores drained (vmcnt0 before barrier)
    if (threadIdx.x == 0)
        __hip_atomic_fetch_add(c, 1, __ATOMIC_RELEASE, __HIP_MEMORY_SCOPE_AGENT);
}

// 512 WGs x 256 thr, 64KB LDS (Wjh+Wkh slices), 2 WGs/CU.
// WG(g): iblk = g&7 (64 batch rows, XCD-local group), lblk = g>>3 (16 gate cols).
// lblk<32 WGs additionally compute 16 out cols (Wo streamed from global).
__global__ __launch_bounds__(256, 2)
void flipflop_rnn_kernel(const float* __restrict__ x,  const float* __restrict__ h0,
                         const float* __restrict__ Wjx, const float* __restrict__ bjx,
                         const float* __restrict__ Wjh, const float* __restrict__ bjh,
                         const float* __restrict__ Wkx, const float* __restrict__ bkx,
                         const float* __restrict__ Wkh, const float* __restrict__ bkh,
                         const float* __restrict__ Wo,  const float* __restrict__ bo,
                         const int* __restrict__ seqlen,
                         float* __restrict__ out,
                         bf16_t* __restrict__ wjh_bf, bf16_t* __restrict__ wkh_bf,
                         bf16_t* __restrict__ wo_bf,  bf16_t* __restrict__ wjx_bf,
                         bf16_t* __restrict__ wkx_bf, bf16_t* __restrict__ x_bf,
                         bf16_t* __restrict__ hbf0,   bf16_t* __restrict__ hbf1,
                         int* __restrict__ cnt)
{
    // [gate][kb 0..127][col 0..15][8 shorts] = 65536 B
    __shared__ short lds_w[32768];

    const int T    = seqlen[0];
    const int tid  = threadIdx.x;
    const int g    = blockIdx.x;
    const int nthr = gridDim.x * blockDim.x;
    const int gtid = g * blockDim.x + tid;

    // ---- cast weights & x to bf16; zero barrier counters ----
    for (int idx = gtid; idx < H * H; idx += nthr) wjh_bf[idx] = __float2bfloat16(Wjh[idx]);
    for (int idx = gtid; idx < H * H; idx += nthr) wkh_bf[idx] = __float2bfloat16(Wkh[idx]);
    for (int idx = gtid; idx < O * H; idx += nthr) wo_bf[idx]  = __float2bfloat16(Wo[idx]);
    for (int idx = gtid; idx < H * I; idx += nthr) wjx_bf[idx] = __float2bfloat16(Wjx[idx]);
    for (int idx = gtid; idx < H * I; idx += nthr) wkx_bf[idx] = __float2bfloat16(Wkx[idx]);
    for (int idx = gtid; idx < B * I; idx += nthr) x_bf[idx]   = __float2bfloat16(x[idx]);
    if (gtid < 8 * 256) cnt[gtid] = 0;

    // ---- geometry ----
    const int w     = tid >> 6;
    const int lane  = tid & 63;
    const int quad  = lane >> 4;
    const int lm    = lane & 15;
    const int iblk  = g & 7;            // XCD-local group id
    const int lblk  = g >> 3;           // 0..63
    const int rbase = iblk * 64 + w * 16;
    const int n0    = lblk * 16;        // gate cols
    const bool has_out = (lblk < 32);
    const int no0   = lblk * 16;        // out cols (valid when has_out)
    int* grp_cnt = cnt + iblk * 256;

    // ---- h0 init: each thread owns 4 (row,col) elements ----
    float hreg[4];
    #pragma unroll
    for (int r = 0; r < 4; ++r) {
        const int row = rbase + quad * 4 + r;
        const int col = n0 + lm;
        const float hv = h0[row * H + col];
        hreg[r] = hv;
        hbf0[row * H + col] = __float2bfloat16(hv);
    }

    cg::this_grid().sync();   // casts + h0 + cnt zero visible device-wide

    // ---- load this WG's Wjh/Wkh rows into LDS (one time) ----
    for (int c = tid; c < 4096; c += 256) {
        const int gate = c >> 11;
        const int cc   = c & 2047;
        const int kb   = cc >> 4;
        const int col  = cc & 15;
        const bf16_t* src = (gate ? wkh_bf : wjh_bf) + (n0 + col) * H + kb * 8;
        *reinterpret_cast<short8*>(&lds_w[c * 8]) = *reinterpret_cast<const short8*>(src);
    }
    __syncthreads();

    // ---- jx/kx (+ all biases) in registers ----
    float jxr[4], kxr[4];
    {
        f32x4 aJ = {0.f, 0.f, 0.f, 0.f};
        f32x4 aK = {0.f, 0.f, 0.f, 0.f};
        const bf16_t* aP = x_bf   + (rbase + lm) * I + quad * 8;
        const bf16_t* jP = wjx_bf + (n0 + lm) * I + quad * 8;
        const bf16_t* kP = wkx_bf + (n0 + lm) * I + quad * 8;
        #pragma unroll 4
        for (int k0 = 0; k0 < I; k0 += 32) {
            short8 a = ldfrag(aP + k0);
            aJ = __builtin_amdgcn_mfma_f32_16x16x32_bf16(a, ldfrag(jP + k0), aJ, 0, 0, 0);
            aK = __builtin_amdgcn_mfma_f32_16x16x32_bf16(a, ldfrag(kP + k0), aK, 0, 0, 0);
        }
        const int col = n0 + lm;
        #pragma unroll
        for (int r = 0; r < 4; ++r) {
            jxr[r] = aJ[r] + bjx[col] + bjh[col];
            kxr[r] = aK[r] + bkx[col] + bkh[col];
        }
    }
    const float bo_v = has_out ? bo[no0 + lm] : 0.0f;

    // ---- recurrence: step t reads h_t, computes h_{t+1} and out_{t-1} ----
    for (int t = 0; t < T; ++t) {
        if (t > 0) group_wait(grp_cnt + t, 64);   // h_t published by all 64 group WGs
        const bf16_t* hb  = (t & 1) ? hbf1 : hbf0;
        bf16_t*       hbn = (t & 1) ? hbf0 : hbf1;

        f32x4 accJ = {0.f, 0.f, 0.f, 0.f};
        f32x4 accK = {0.f, 0.f, 0.f, 0.f};
        f32x4 accO = {0.f, 0.f, 0.f, 0.f};

        const bf16_t* aP = hb    + (rbase + lm) * H + quad * 8;
        const bf16_t* oP = wo_bf + (no0 + lm) * H + quad * 8;
        const short*  jL = lds_w + quad * 128 + lm * 8;          // [kb][col][8]
        const short*  kL = jL + 16384;

        if (has_out) {
            #pragma unroll 4
            for (int k0 = 0; k0 < H; k0 += 32) {
                short8 a  = ldfrag(aP + k0);
                short8 bj = *reinterpret_cast<const short8*>(jL + (k0 >> 3) * 128);
                short8 bk = *reinterpret_cast<const short8*>(kL + (k0 >> 3) * 128);
                accJ = __builtin_amdgcn_mfma_f32_16x16x32_bf16(a, bj, accJ, 0, 0, 0);
                accK = __builtin_amdgcn_mfma_f32_16x16x32_bf16(a, bk, accK, 0, 0, 0);
                accO = __builtin_amdgcn_mfma_f32_16x16x32_bf16(a, ldfrag(oP + k0), accO, 0, 0, 0);
            }
        } else {
            #pragma unroll 4
            for (int k0 = 0; k0 < H; k0 += 32) {
                short8 a  = ldfrag(aP + k0);
                short8 bj = *reinterpret_cast<const short8*>(jL + (k0 >> 3) * 128);
                short8 bk = *reinterpret_cast<const short8*>(kL + (k0 >> 3) * 128);
                accJ = __builtin_amdgcn_mfma_f32_16x16x32_bf16(a, bj, accJ, 0, 0, 0);
                accK = __builtin_amdgcn_mfma_f32_16x16x32_bf16(a, bk, accK, 0, 0, 0);
            }
        }

        if (has_out && t > 0) {
            #pragma unroll
            for (int r = 0; r < 4; ++r) {
                const int row = rbase + quad * 4 + r;
                out[(row * T + (t - 1)) * O + no0 + lm] = accO[r] + bo_v;
            }
        }

        #pragma unroll
        for (int r = 0; r < 4; ++r) {
            const int row = rbase + quad * 4 + r;
            const int col = n0 + lm;
            const float jv = sigmoid_f(accJ[r] + jxr[r]);
            const float kv = sigmoid_f(accK[r] + kxr[r]);
            const float hv = hreg[r];
            const float hn = jv * (1.0f - hv) + (1.0f - kv) * hv;
            hreg[r] = hn;
            hbn[row * H + col] = __float2bfloat16(hn);
        }

        group_post(grp_cnt + t + 1);   // publish h_{t+1}
    }

    group_wait(grp_cnt + T, 64);       // h_T published

    // ---- epilogue: out_{T-1} and h_final ----
    {
        const bf16_t* hb = (T & 1) ? hbf1 : hbf0;
        if (has_out) {
            f32x4 accO = {0.f, 0.f, 0.f, 0.f};
            const bf16_t* aP = hb    + (rbase + lm) * H + quad * 8;
            const bf16_t* oP = wo_bf + (no0 + lm) * H + quad * 8;
            #pragma unroll 4
            for (int k0 = 0; k0 < H; k0 += 32) {
                accO = __builtin_amdgcn_mfma_f32_16x16x32_bf16(ldfrag(aP + k0), ldfrag(oP + k0), accO, 0, 0, 0);
            }
            #pragma unroll
            for (int r = 0; r < 4; ++r) {
                const int row = rbase + quad * 4 + r;
                out[(row * T + (T - 1)) * O + no0 + lm] = accO[r] + bo_v;
            }
        }
        const int hfin = B * T * O;
        #pragma unroll
        for (int r = 0; r < 4; ++r) {
            const int row = rbase + quad * 4 + r;
            const int col = n0 + lm;
            out[hfin + row * H + col] = hreg[r];
        }
    }
}

extern "C" void kernel_launch(void* const* d_in, const int* in_sizes, int n_in,
                              void* d_out, int out_size, void* d_ws, size_t ws_size,
                              hipStream_t stream) {
    const float* x   = (const float*)d_in[0];
    const float* h0  = (const float*)d_in[1];
    const float* Wjx = (const float*)d_in[2];
    const float* bjx = (const float*)d_in[3];
    const float* Wjh = (const float*)d_in[4];
    const float* bjh = (const float*)d_in[5];
    const float* Wkx = (const float*)d_in[6];
    const float* bkx = (const float*)d_in[7];
    const float* Wkh = (const float*)d_in[8];
    const float* bkh = (const float*)d_in[9];
    const float* Wo  = (const float*)d_in[10];
    const float* bo  = (const float*)d_in[11];
    const int* seqlen = (const int*)d_in[12];
    float* out = (float*)d_out;

    // workspace layout (bytes)
    char* ws = (char*)d_ws;
    bf16_t* wjh_bf = (bf16_t*)(ws + 0);                 // 2 MB
    bf16_t* wkh_bf = (bf16_t*)(ws + 2097152);           // 2 MB
    bf16_t* wo_bf  = (bf16_t*)(ws + 4194304);           // 1 MB
    bf16_t* wjx_bf = (bf16_t*)(ws + 5242880);           // 1 MB
    bf16_t* wkx_bf = (bf16_t*)(ws + 6291456);           // 1 MB
    bf16_t* x_bf   = (bf16_t*)(ws + 7340032);           // 0.5 MB
    bf16_t* hbf0   = (bf16_t*)(ws + 7864320);           // 1 MB
    bf16_t* hbf1   = (bf16_t*)(ws + 8912896);           // 1 MB
    int*    cnt    = (int*)   (ws + 9961472);           // 8 KB barrier counters

    void* args[] = {
        &x, &h0, &Wjx, &bjx, &Wjh, &bjh, &Wkx, &bkx, &Wkh, &bkh, &Wo, &bo,
        &seqlen, &out,
        &wjh_bf, &wkh_bf, &wo_bf, &wjx_bf, &wkx_bf, &x_bf, &hbf0, &hbf1, &cnt
    };
    hipLaunchCooperativeKernel((const void*)flipflop_rnn_kernel,
                               dim3(512), dim3(256), args, 0, stream);
}

// Round 4
// 1988.053 us; speedup vs baseline: 3.4867x; 2.7681x over previous
//
#include <hip/hip_runtime.h>
#include <hip/hip_bf16.h>
#include <hip/hip_cooperative_groups.h>

namespace cg = cooperative_groups;

constexpr int B = 512;
constexpr int I = 512;
constexpr int H = 1024;
constexpr int O = 512;

using short8 = __attribute__((ext_vector_type(8))) short;
using f32x4  = __attribute__((ext_vector_type(4))) float;
using bf16_t = __hip_bfloat16;

__device__ __forceinline__ short8 ldfrag(const bf16_t* p) {
    return *reinterpret_cast<const short8*>(p);
}
__device__ __forceinline__ float sigmoid_f(float z) {
    return 1.0f / (1.0f + __expf(-z));
}

// Per-iblk group barrier. Group = 64 WGs with the same (blockIdx % 8), which
// under MI355X round-robin dispatch all live on ONE XCD -> the XCD L2 is the
// coherence point for the group's h exchange. No wbl2 / L2-inv needed; only
// the per-CU L1 must be invalidated (stale double-buffer lines).
// Counters are relaxed agent-scope atomics (LLC). h stores are drained to the
// local L2 by __syncthreads' implicit vmcnt(0) before the post.
__device__ __forceinline__ void group_wait(int* c, int target) {
    if (threadIdx.x == 0) {
        while (__hip_atomic_load(c, __ATOMIC_RELAXED, __HIP_MEMORY_SCOPE_AGENT) < target)
            __builtin_amdgcn_s_sleep(2);
    }
    __syncthreads();
    asm volatile("buffer_inv sc0" ::: "memory");   // L1-only invalidate
}
__device__ __forceinline__ void group_post(int* c) {
    __syncthreads();  // drains this WG's h stores to local L2 (vmcnt 0)
    if (threadIdx.x == 0)
        __hip_atomic_fetch_add(c, 1, __ATOMIC_RELAXED, __HIP_MEMORY_SCOPE_AGENT);
}

// 512 WGs x 256 thr, 64KB LDS (Wjh+Wkh slices), 2 WGs/CU.
// WG(g): iblk = g&7 (64 batch rows, XCD-local group), lblk = g>>3 (16 gate cols).
// lblk<32 WGs additionally compute 16 out cols (Wo streamed from L2).
__global__ __launch_bounds__(256, 2)
void flipflop_rnn_kernel(const float* __restrict__ x,  const float* __restrict__ h0,
                         const float* __restrict__ Wjx, const float* __restrict__ bjx,
                         const float* __restrict__ Wjh, const float* __restrict__ bjh,
                         const float* __restrict__ Wkx, const float* __restrict__ bkx,
                         const float* __restrict__ Wkh, const float* __restrict__ bkh,
                         const float* __restrict__ Wo,  const float* __restrict__ bo,
                         const int* __restrict__ seqlen,
                         float* __restrict__ out,
                         bf16_t* __restrict__ wjh_bf, bf16_t* __restrict__ wkh_bf,
                         bf16_t* __restrict__ wo_bf,  bf16_t* __restrict__ wjx_bf,
                         bf16_t* __restrict__ wkx_bf, bf16_t* __restrict__ x_bf,
                         bf16_t* __restrict__ hbf0,   bf16_t* __restrict__ hbf1,
                         int* __restrict__ cnt)
{
    // [gate][kb 0..127][col 0..15][8 shorts] = 65536 B
    __shared__ short lds_w[32768];

    const int T    = seqlen[0];
    const int tid  = threadIdx.x;
    const int g    = blockIdx.x;
    const int nthr = gridDim.x * blockDim.x;
    const int gtid = g * blockDim.x + tid;

    // ---- cast weights & x to bf16; zero barrier counters ----
    for (int idx = gtid; idx < H * H; idx += nthr) wjh_bf[idx] = __float2bfloat16(Wjh[idx]);
    for (int idx = gtid; idx < H * H; idx += nthr) wkh_bf[idx] = __float2bfloat16(Wkh[idx]);
    for (int idx = gtid; idx < O * H; idx += nthr) wo_bf[idx]  = __float2bfloat16(Wo[idx]);
    for (int idx = gtid; idx < H * I; idx += nthr) wjx_bf[idx] = __float2bfloat16(Wjx[idx]);
    for (int idx = gtid; idx < H * I; idx += nthr) wkx_bf[idx] = __float2bfloat16(Wkx[idx]);
    for (int idx = gtid; idx < B * I; idx += nthr) x_bf[idx]   = __float2bfloat16(x[idx]);
    if (gtid < 8 * 256) cnt[gtid] = 0;

    // ---- geometry ----
    const int w     = tid >> 6;
    const int lane  = tid & 63;
    const int quad  = lane >> 4;
    const int lm    = lane & 15;
    const int iblk  = g & 7;            // XCD-local group id
    const int lblk  = g >> 3;           // 0..63
    const int rbase = iblk * 64 + w * 16;
    const int n0    = lblk * 16;        // gate cols
    const bool has_out = (lblk < 32);
    const int no0   = lblk * 16;        // out cols (valid when has_out)
    int* grp_cnt = cnt + iblk * 256;

    // ---- h0 init: each thread owns 4 (row,col) elements ----
    float hreg[4];
    #pragma unroll
    for (int r = 0; r < 4; ++r) {
        const int row = rbase + quad * 4 + r;
        const int col = n0 + lm;
        const float hv = h0[row * H + col];
        hreg[r] = hv;
        hbf0[row * H + col] = __float2bfloat16(hv);
    }

    cg::this_grid().sync();   // casts + h0 + cnt zero visible device-wide

    // ---- load this WG's Wjh/Wkh rows into LDS (one time) ----
    for (int c = tid; c < 4096; c += 256) {
        const int gate = c >> 11;
        const int cc   = c & 2047;
        const int kb   = cc >> 4;
        const int col  = cc & 15;
        const bf16_t* src = (gate ? wkh_bf : wjh_bf) + (n0 + col) * H + kb * 8;
        *reinterpret_cast<short8*>(&lds_w[c * 8]) = *reinterpret_cast<const short8*>(src);
    }
    __syncthreads();

    // ---- jx/kx (+ all biases) in registers ----
    float jxr[4], kxr[4];
    {
        f32x4 aJ = {0.f, 0.f, 0.f, 0.f};
        f32x4 aK = {0.f, 0.f, 0.f, 0.f};
        const bf16_t* aP = x_bf   + (rbase + lm) * I + quad * 8;
        const bf16_t* jP = wjx_bf + (n0 + lm) * I + quad * 8;
        const bf16_t* kP = wkx_bf + (n0 + lm) * I + quad * 8;
        #pragma unroll 4
        for (int k0 = 0; k0 < I; k0 += 32) {
            short8 a = ldfrag(aP + k0);
            aJ = __builtin_amdgcn_mfma_f32_16x16x32_bf16(a, ldfrag(jP + k0), aJ, 0, 0, 0);
            aK = __builtin_amdgcn_mfma_f32_16x16x32_bf16(a, ldfrag(kP + k0), aK, 0, 0, 0);
        }
        const int col = n0 + lm;
        #pragma unroll
        for (int r = 0; r < 4; ++r) {
            jxr[r] = aJ[r] + bjx[col] + bjh[col];
            kxr[r] = aK[r] + bkx[col] + bkh[col];
        }
    }
    const float bo_v = has_out ? bo[no0 + lm] : 0.0f;

    // ---- recurrence: step t reads h_t, computes h_{t+1} and out_{t-1} ----
    for (int t = 0; t < T; ++t) {
        if (t > 0) group_wait(grp_cnt + t, 64);   // h_t published by all 64 group WGs
        const bf16_t* hb  = (t & 1) ? hbf1 : hbf0;
        bf16_t*       hbn = (t & 1) ? hbf0 : hbf1;

        f32x4 accJ = {0.f, 0.f, 0.f, 0.f};
        f32x4 accK = {0.f, 0.f, 0.f, 0.f};
        f32x4 accO = {0.f, 0.f, 0.f, 0.f};

        const bf16_t* aP = hb    + (rbase + lm) * H + quad * 8;
        const bf16_t* oP = wo_bf + (no0 + lm) * H + quad * 8;
        const short*  jL = lds_w + quad * 128 + lm * 8;          // [kb][col][8]
        const short*  kL = jL + 16384;

        if (has_out) {
            #pragma unroll 4
            for (int k0 = 0; k0 < H; k0 += 32) {
                short8 a  = ldfrag(aP + k0);
                short8 bj = *reinterpret_cast<const short8*>(jL + (k0 >> 3) * 128);
                short8 bk = *reinterpret_cast<const short8*>(kL + (k0 >> 3) * 128);
                accJ = __builtin_amdgcn_mfma_f32_16x16x32_bf16(a, bj, accJ, 0, 0, 0);
                accK = __builtin_amdgcn_mfma_f32_16x16x32_bf16(a, bk, accK, 0, 0, 0);
                accO = __builtin_amdgcn_mfma_f32_16x16x32_bf16(a, ldfrag(oP + k0), accO, 0, 0, 0);
            }
        } else {
            #pragma unroll 4
            for (int k0 = 0; k0 < H; k0 += 32) {
                short8 a  = ldfrag(aP + k0);
                short8 bj = *reinterpret_cast<const short8*>(jL + (k0 >> 3) * 128);
                short8 bk = *reinterpret_cast<const short8*>(kL + (k0 >> 3) * 128);
                accJ = __builtin_amdgcn_mfma_f32_16x16x32_bf16(a, bj, accJ, 0, 0, 0);
                accK = __builtin_amdgcn_mfma_f32_16x16x32_bf16(a, bk, accK, 0, 0, 0);
            }
        }

        if (has_out && t > 0) {
            #pragma unroll
            for (int r = 0; r < 4; ++r) {
                const int row = rbase + quad * 4 + r;
                out[(row * T + (t - 1)) * O + no0 + lm] = accO[r] + bo_v;
            }
        }

        #pragma unroll
        for (int r = 0; r < 4; ++r) {
            const int row = rbase + quad * 4 + r;
            const int col = n0 + lm;
            const float jv = sigmoid_f(accJ[r] + jxr[r]);
            const float kv = sigmoid_f(accK[r] + kxr[r]);
            const float hv = hreg[r];
            const float hn = jv * (1.0f - hv) + (1.0f - kv) * hv;
            hreg[r] = hn;
            hbn[row * H + col] = __float2bfloat16(hn);
        }

        group_post(grp_cnt + t + 1);   // publish h_{t+1}
    }

    group_wait(grp_cnt + T, 64);       // h_T published

    // ---- epilogue: out_{T-1} and h_final ----
    {
        const bf16_t* hb = (T & 1) ? hbf1 : hbf0;
        if (has_out) {
            f32x4 accO = {0.f, 0.f, 0.f, 0.f};
            const bf16_t* aP = hb    + (rbase + lm) * H + quad * 8;
            const bf16_t* oP = wo_bf + (no0 + lm) * H + quad * 8;
            #pragma unroll 4
            for (int k0 = 0; k0 < H; k0 += 32) {
                accO = __builtin_amdgcn_mfma_f32_16x16x32_bf16(ldfrag(aP + k0), ldfrag(oP + k0), accO, 0, 0, 0);
            }
            #pragma unroll
            for (int r = 0; r < 4; ++r) {
                const int row = rbase + quad * 4 + r;
                out[(row * T + (T - 1)) * O + no0 + lm] = accO[r] + bo_v;
            }
        }
        const int hfin = B * T * O;
        #pragma unroll
        for (int r = 0; r < 4; ++r) {
            const int row = rbase + quad * 4 + r;
            const int col = n0 + lm;
            out[hfin + row * H + col] = hreg[r];
        }
    }
}

extern "C" void kernel_launch(void* const* d_in, const int* in_sizes, int n_in,
                              void* d_out, int out_size, void* d_ws, size_t ws_size,
                              hipStream_t stream) {
    const float* x   = (const float*)d_in[0];
    const float* h0  = (const float*)d_in[1];
    const float* Wjx = (const float*)d_in[2];
    const float* bjx = (const float*)d_in[3];
    const float* Wjh = (const float*)d_in[4];
    const float* bjh = (const float*)d_in[5];
    const float* Wkx = (const float*)d_in[6];
    const float* bkx = (const float*)d_in[7];
    const float* Wkh = (const float*)d_in[8];
    const float* bkh = (const float*)d_in[9];
    const float* Wo  = (const float*)d_in[10];
    const float* bo  = (const float*)d_in[11];
    const int* seqlen = (const int*)d_in[12];
    float* out = (float*)d_out;

    // workspace layout (bytes)
    char* ws = (char*)d_ws;
    bf16_t* wjh_bf = (bf16_t*)(ws + 0);                 // 2 MB
    bf16_t* wkh_bf = (bf16_t*)(ws + 2097152);           // 2 MB
    bf16_t* wo_bf  = (bf16_t*)(ws + 4194304);           // 1 MB
    bf16_t* wjx_bf = (bf16_t*)(ws + 5242880);           // 1 MB
    bf16_t* wkx_bf = (bf16_t*)(ws + 6291456);           // 1 MB
    bf16_t* x_bf   = (bf16_t*)(ws + 7340032);           // 0.5 MB
    bf16_t* hbf0   = (bf16_t*)(ws + 7864320);           // 1 MB
    bf16_t* hbf1   = (bf16_t*)(ws + 8912896);           // 1 MB
    int*    cnt    = (int*)   (ws + 9961472);           // 8 KB barrier counters

    void* args[] = {
        &x, &h0, &Wjx, &bjx, &Wjh, &bjh, &Wkx, &bkx, &Wkh, &bkh, &Wo, &bo,
        &seqlen, &out,
        &wjh_bf, &wkh_bf, &wo_bf, &wjx_bf, &wkx_bf, &x_bf, &hbf0, &hbf1, &cnt
    };
    hipLaunchCooperativeKernel((const void*)flipflop_rnn_kernel,
                               dim3(512), dim3(256), args, 0, stream);
}